// Round 1
// baseline (558.916 us; speedup 1.0000x reference)
//
#include <hip/hip_runtime.h>
#include <hip/hip_bf16.h>

// Vim (Vision Mamba) block forward, fp32.
// B=4, C=D_MODEL=96, H=W=64 -> L=4096, D_INNER=192, DT_RANK=6, N=16, K=4.
// Pipeline:
//   k1: RMSNorm + in-proj (96->384) -> xz
//   k2: causal depthwise conv(K=4)+bias+SiLU + x-proj (192->38) + dt-proj(6->192)+softplus
//   k3a/k3b/k3c: chunked selective scan (32 chunks of 128)
//   k4: y=(yscan+D*xs)*silu(z); out-proj (192->96) + residual u

#define DM   96
#define DI   192
#define LSEQ 4096
#define NB   4
#define RNK  6
#define NST  16
#define NC   32      // chunks
#define CS   128     // chunk size

// ---------------- k1: RMSNorm + in-proj ----------------
// grid 2048 (8 tokens/block), block 256. tid = t*32+s, t in [0,8), s in [0,32)
__global__ __launch_bounds__(256) void k1_inproj(const float* __restrict__ x,
                                                 const float* __restrict__ W_in,
                                                 const float* __restrict__ norm_w,
                                                 float* __restrict__ xz) {
    int blk = blockIdx.x;
    int b = blk >> 9;            // 512 blocks per batch
    int l0 = (blk & 511) * 8;
    int tid = threadIdx.x;
    int t = tid >> 5, s = tid & 31;
    __shared__ float xn[8][96];

    int l = l0 + t;
    const float* xb = x + (size_t)b * DM * LSEQ + l;
    float uv[3];
    float ss = 0.f;
#pragma unroll
    for (int k = 0; k < 3; k++) {
        int c = s + 32 * k;
        float v = xb[(size_t)c * LSEQ];
        uv[k] = v;
        ss += v * v;
    }
    // reduce over the 32 lanes of this token (stays within a 32-lane half-wave)
#pragma unroll
    for (int off = 16; off >= 1; off >>= 1) ss += __shfl_xor(ss, off, 64);
    float rstd = rsqrtf(ss * (1.0f / DM) + 1e-5f);
#pragma unroll
    for (int k = 0; k < 3; k++) {
        int c = s + 32 * k;
        xn[t][c] = uv[k] * rstd * norm_w[c];
    }
    __syncthreads();

    // each thread: token t, outputs j = s + 32*k, k=0..11 (384 outputs/token)
    float acc[12];
#pragma unroll
    for (int k = 0; k < 12; k++) acc[k] = 0.f;
    for (int c4 = 0; c4 < 96; c4 += 4) {
        float4 xv = *(const float4*)&xn[t][c4];
#pragma unroll
        for (int k = 0; k < 12; k++) {
            const float4 w = *(const float4*)&W_in[(size_t)(s + 32 * k) * 96 + c4];
            acc[k] += xv.x * w.x + xv.y * w.y + xv.z * w.z + xv.w * w.w;
        }
    }
    float* o = xz + ((size_t)(b * LSEQ + l)) * 384;
#pragma unroll
    for (int k = 0; k < 12; k++) o[s + 32 * k] = acc[k];
}

// ---------------- k2: conv + SiLU + x-proj + dt-proj ----------------
// grid 1024 (16 tokens/block), block 256
__global__ __launch_bounds__(256) void k2_conv_proj(const float* __restrict__ xz,
                                                    const float* __restrict__ conv_w,
                                                    const float* __restrict__ conv_b,
                                                    const float* __restrict__ W_x,
                                                    const float* __restrict__ W_dt,
                                                    const float* __restrict__ b_dt,
                                                    float* __restrict__ xs_g,
                                                    float* __restrict__ delta_g,
                                                    float* __restrict__ Bm_g,
                                                    float* __restrict__ Cm_g) {
    int blk = blockIdx.x;
    int b = blk >> 8;            // 256 blocks per batch
    int l0 = (blk & 255) * 16;
    int tid = threadIdx.x;
    __shared__ float pre[19][192];   // rows l0-3 .. l0+15
    __shared__ float xsl[16][192];
    __shared__ float dbc[16][38];

    for (int i = tid; i < 19 * 192; i += 256) {
        int r = i / 192, e = i % 192;
        int l = l0 - 3 + r;
        pre[r][e] = (l >= 0) ? xz[((size_t)(b * LSEQ + l)) * 384 + e] : 0.f;
    }
    __syncthreads();

    for (int i = tid; i < 16 * 192; i += 256) {
        int lt = i / 192, e = i % 192;
        float v = conv_b[e];
#pragma unroll
        for (int k = 0; k < 4; k++) v += conv_w[e * 4 + k] * pre[lt + k][e];
        float sil = v / (1.f + __expf(-v));
        xsl[lt][e] = sil;
        xs_g[((size_t)(b * LSEQ + l0 + lt)) * DI + e] = sil;
    }
    __syncthreads();

    for (int i = tid; i < 16 * 38; i += 256) {
        int lt = i / 38, o = i % 38;
        float a = 0.f;
        const float* wr = &W_x[(size_t)o * DI];
        for (int e = 0; e < DI; e += 4) {
            float4 xv = *(const float4*)&xsl[lt][e];
            float4 w  = *(const float4*)&wr[e];
            a += xv.x * w.x + xv.y * w.y + xv.z * w.z + xv.w * w.w;
        }
        dbc[lt][o] = a;
    }
    __syncthreads();

    for (int i = tid; i < 16 * 192; i += 256) {
        int lt = i / 192, e = i % 192;
        float a = b_dt[e];
#pragma unroll
        for (int r = 0; r < RNK; r++) a += dbc[lt][r] * W_dt[e * RNK + r];
        float d = (a > 20.f) ? a : log1pf(__expf(a));
        delta_g[((size_t)(b * LSEQ + l0 + lt)) * DI + e] = d;
    }
    for (int i = tid; i < 16 * 32; i += 256) {
        int lt = i / 32, o = i % 32;
        float v = dbc[lt][RNK + o];
        size_t base = ((size_t)(b * LSEQ + l0 + lt)) * NST;
        if (o < NST) Bm_g[base + o] = v;
        else         Cm_g[base + (o - NST)] = v;
    }
}

// ---------------- k3a: per-chunk aggregates ----------------
// groups: g = (b*NC + c)*DI + e, 16 lanes = n. grid 1536, block 256.
__global__ __launch_bounds__(256) void k3a_chunk(const float* __restrict__ delta_g,
                                                 const float* __restrict__ xs_g,
                                                 const float* __restrict__ Bm_g,
                                                 const float* __restrict__ A_log,
                                                 float* __restrict__ Ap_g,
                                                 float* __restrict__ Bs_g) {
    int gid = blockIdx.x * 16 + (threadIdx.x >> 4);
    int n = threadIdx.x & 15;
    int e = gid % DI;
    int t = gid / DI;
    int c = t & (NC - 1);
    int b = t >> 5;

    float A_th = -__expf(A_log[e * NST + n]);
    size_t lbase = (size_t)b * LSEQ + (size_t)c * CS;
    const float* dp = delta_g + lbase * DI + e;
    const float* xp = xs_g + lbase * DI + e;
    const float* bp = Bm_g + lbase * NST + n;

    float ap = 1.f, bs = 0.f;
    for (int l = 0; l < CS; l++) {
        float d = dp[(size_t)l * DI];
        float xv = xp[(size_t)l * DI];
        float bm = bp[(size_t)l * NST];
        float a = __expf(d * A_th);
        ap *= a;
        bs = bs * a + d * xv * bm;
    }
    size_t idx = (((size_t)(b * DI + e)) * NC + c) * NST + n;
    Ap_g[idx] = ap;
    Bs_g[idx] = bs;
}

// ---------------- k3b: scan over chunk aggregates ----------------
// 12288 threads: i = (b*DI+e)*NST + n. grid 48, block 256.
__global__ __launch_bounds__(256) void k3b_combine(const float* __restrict__ Ap_g,
                                                   const float* __restrict__ Bs_g,
                                                   float* __restrict__ h0_g) {
    int i = blockIdx.x * 256 + threadIdx.x;
    int n = i & 15;
    int be = i >> 4;
    size_t base = ((size_t)be * NC) * NST + n;
    float h = 0.f;
    for (int c = 0; c < NC; c++) {
        h0_g[base + (size_t)c * NST] = h;
        h = Ap_g[base + (size_t)c * NST] * h + Bs_g[base + (size_t)c * NST];
    }
}

// ---------------- k3c: within-chunk recompute + y ----------------
__global__ __launch_bounds__(256) void k3c_scan(const float* __restrict__ delta_g,
                                                const float* __restrict__ xs_g,
                                                const float* __restrict__ Bm_g,
                                                const float* __restrict__ Cm_g,
                                                const float* __restrict__ A_log,
                                                const float* __restrict__ h0_g,
                                                float* __restrict__ yscan_g) {
    int gid = blockIdx.x * 16 + (threadIdx.x >> 4);
    int n = threadIdx.x & 15;
    int e = gid % DI;
    int t = gid / DI;
    int c = t & (NC - 1);
    int b = t >> 5;

    float A_th = -__expf(A_log[e * NST + n]);
    float h = h0_g[(((size_t)(b * DI + e)) * NC + c) * NST + n];
    size_t lbase = (size_t)b * LSEQ + (size_t)c * CS;
    const float* dp = delta_g + lbase * DI + e;
    const float* xp = xs_g + lbase * DI + e;
    const float* bp = Bm_g + lbase * NST + n;
    const float* cp = Cm_g + lbase * NST + n;
    float* yp = yscan_g + lbase * DI + e;

    for (int l = 0; l < CS; l++) {
        float d = dp[(size_t)l * DI];
        float xv = xp[(size_t)l * DI];
        float bm = bp[(size_t)l * NST];
        float cm = cp[(size_t)l * NST];
        float a = __expf(d * A_th);
        h = a * h + d * xv * bm;
        float y = h * cm;
        y += __shfl_xor(y, 1, 64);
        y += __shfl_xor(y, 2, 64);
        y += __shfl_xor(y, 4, 64);
        y += __shfl_xor(y, 8, 64);
        if (n == 0) yp[(size_t)l * DI] = y;
    }
}

// ---------------- k4: gate + out-proj + residual ----------------
// grid 2048 (8 tokens/block), block 256. tid = t*32+s
__global__ __launch_bounds__(256) void k4_outproj(const float* __restrict__ x,
                                                  const float* __restrict__ xz,
                                                  const float* __restrict__ xs_g,
                                                  const float* __restrict__ yscan_g,
                                                  const float* __restrict__ D_param,
                                                  const float* __restrict__ W_out,
                                                  float* __restrict__ out) {
    int blk = blockIdx.x;
    int b = blk >> 9;
    int l0 = (blk & 511) * 8;
    int tid = threadIdx.x;
    int t = tid >> 5, s = tid & 31;
    __shared__ float yl[8][192];

    int l = l0 + t;
    size_t tb = (size_t)(b * LSEQ + l);
#pragma unroll
    for (int k = 0; k < 6; k++) {
        int e = s + 32 * k;
        float ys = yscan_g[tb * DI + e];
        float xv = xs_g[tb * DI + e];
        float z = xz[tb * 384 + 192 + e];
        float y = (ys + D_param[e] * xv) * (z / (1.f + __expf(-z)));
        yl[t][e] = y;
    }
    __syncthreads();

    float acc[3];
#pragma unroll
    for (int k = 0; k < 3; k++) acc[k] = 0.f;
    for (int e4 = 0; e4 < 192; e4 += 4) {
        float4 yv = *(const float4*)&yl[t][e4];
#pragma unroll
        for (int k = 0; k < 3; k++) {
            const float4 w = *(const float4*)&W_out[(size_t)(s + 32 * k) * 192 + e4];
            acc[k] += yv.x * w.x + yv.y * w.y + yv.z * w.z + yv.w * w.w;
        }
    }
#pragma unroll
    for (int k = 0; k < 3; k++) {
        int cch = s + 32 * k;
        size_t oi = ((size_t)(b * DM + cch)) * LSEQ + l;
        out[oi] = acc[k] + x[oi];
    }
}

extern "C" void kernel_launch(void* const* d_in, const int* in_sizes, int n_in,
                              void* d_out, int out_size, void* d_ws, size_t ws_size,
                              hipStream_t stream) {
    const float* x      = (const float*)d_in[0];
    const float* W_in   = (const float*)d_in[1];
    const float* conv_w = (const float*)d_in[2];
    const float* conv_b = (const float*)d_in[3];
    const float* W_x    = (const float*)d_in[4];
    const float* W_dt   = (const float*)d_in[5];
    const float* b_dt   = (const float*)d_in[6];
    const float* A_log  = (const float*)d_in[7];
    const float* D_par  = (const float*)d_in[8];
    const float* W_out  = (const float*)d_in[9];
    const float* norm_w = (const float*)d_in[10];
    float* out = (float*)d_out;
    float* ws  = (float*)d_ws;

    // ws layout (floats)
    float* xz    = ws;                      // 16384*384   = 6291456
    float* xs    = ws + 6291456;            // 16384*192   = 3145728
    float* delta = ws + 9437184;            // 3145728
    float* Bm    = ws + 12582912;           // 16384*16    = 262144
    float* Cm    = ws + 12845056;           // 262144
    float* Ap    = ws + 13107200;           // 4*192*32*16 = 393216
    float* Bs    = ws + 13500416;           // 393216
    float* h0    = ws + 13893632;           // 393216
    float* ysc   = ws + 14286848;           // 3145728  -> total 17432576 floats (~70 MB)

    k1_inproj<<<2048, 256, 0, stream>>>(x, W_in, norm_w, xz);
    k2_conv_proj<<<1024, 256, 0, stream>>>(xz, conv_w, conv_b, W_x, W_dt, b_dt,
                                           xs, delta, Bm, Cm);
    k3a_chunk<<<1536, 256, 0, stream>>>(delta, xs, Bm, A_log, Ap, Bs);
    k3b_combine<<<48, 256, 0, stream>>>(Ap, Bs, h0);
    k3c_scan<<<1536, 256, 0, stream>>>(delta, xs, Bm, Cm, A_log, h0, ysc);
    k4_outproj<<<2048, 256, 0, stream>>>(x, xz, xs, ysc, D_par, W_out, out);
}

// Round 2
// 300.693 us; speedup vs baseline: 1.8588x; 1.8588x over previous
//
#include <hip/hip_runtime.h>
#include <hip/hip_bf16.h>

// Vim (Vision Mamba) block forward, fp32.
// B=4, C=D_MODEL=96, L=4096, D_INNER=192, DT_RANK=6, N=16, K=4.
//   k1: RMSNorm + in-proj (96->384)        [token-per-lane, uniform W loads]
//   k2: conv(K=4)+SiLU + x-proj + dt-proj  [W_x/W_dt staged in LDS]
//   k3a/k3b/k3c: chunked selective scan (32 chunks of 128); k3c fuses gating,
//                writes g transposed [e][l]
//   k4: out-proj (192->96) + residual      [token-per-lane, uniform W loads]

#define DM   96
#define DI   192
#define LSEQ 4096
#define NB   4
#define RNK  6
#define NST  16
#define NC   32
#define CS   128

// ---------------- k1: RMSNorm + in-proj ----------------
// grid 512 = 256 token-groups x 2 j-halves; block 256 (4 waves).
// lane = token within group of 64; wave w handles 48 outputs.
__global__ __launch_bounds__(256) void k1_inproj(const float* __restrict__ x,
                                                 const float* __restrict__ W_in,
                                                 const float* __restrict__ norm_w,
                                                 float* __restrict__ xz) {
    int blk = blockIdx.x;
    int tg = blk >> 1;           // token group 0..255
    int jh = blk & 1;
    int lane = threadIdx.x & 63;
    int wv = __builtin_amdgcn_readfirstlane(threadIdx.x >> 6);
    int b = tg >> 6;                       // 64 groups per batch
    int l = ((tg & 63) << 6) | lane;       // token in [0,4096)

    const float* xb = x + (size_t)b * DM * LSEQ + l;
    float xn[96];
    float ss = 0.f;
#pragma unroll
    for (int c = 0; c < 96; c++) {
        float v = xb[(size_t)c * LSEQ];    // lanes contiguous -> coalesced
        xn[c] = v;
        ss += v * v;
    }
    float rstd = rsqrtf(ss * (1.0f / 96.0f) + 1e-5f);
#pragma unroll
    for (int c = 0; c < 96; c++) xn[c] *= rstd * norm_w[c];

    int j0 = jh * 192 + wv * 48;
    float* o = xz + ((size_t)(b * LSEQ + l)) * 384;
    for (int jc = 0; jc < 12; jc++) {
        int j = j0 + jc * 4;
        const float* w0 = W_in + (size_t)j * 96;   // uniform address -> broadcast
        float a0 = 0.f, a1 = 0.f, a2 = 0.f, a3 = 0.f;
#pragma unroll
        for (int c = 0; c < 96; c++) {
            float xv = xn[c];
            a0 += xv * w0[c];
            a1 += xv * w0[96 + c];
            a2 += xv * w0[192 + c];
            a3 += xv * w0[288 + c];
        }
        float4 r = make_float4(a0, a1, a2, a3);
        *(float4*)&o[j] = r;
    }
}

// ---------------- k2: conv + SiLU + x-proj + dt-proj ----------------
// grid 1024 (16 tokens/block), block 256. W_x/W_dt staged in LDS.
__global__ __launch_bounds__(256) void k2_conv_proj(const float* __restrict__ xz,
                                                    const float* __restrict__ conv_w,
                                                    const float* __restrict__ conv_b,
                                                    const float* __restrict__ W_x,
                                                    const float* __restrict__ W_dt,
                                                    const float* __restrict__ b_dt,
                                                    float* __restrict__ xs_g,
                                                    float* __restrict__ delta_g,
                                                    float* __restrict__ Bm_g,
                                                    float* __restrict__ Cm_g) {
    int blk = blockIdx.x;
    int b = blk >> 8;
    int l0 = (blk & 255) * 16;
    int tid = threadIdx.x;
    __shared__ float pre[19][192];      // 14592 B
    __shared__ float xsl[16][196];      // 12544 B (padded)
    __shared__ float Wx_l[38][196];     // 29792 B (padded)
    __shared__ float Wdt_t[RNK][192];   //  4608 B (transposed)
    __shared__ float dbc[16][38];       //  2432 B

    for (int i = tid; i < 38 * 192; i += 256) Wx_l[i / 192][i % 192] = W_x[i];
    for (int i = tid; i < 192 * RNK; i += 256) Wdt_t[i % RNK][i / RNK] = W_dt[i];
    for (int i = tid; i < 19 * 192; i += 256) {
        int r = i / 192, e = i % 192;
        int l = l0 - 3 + r;
        pre[r][e] = (l >= 0) ? xz[((size_t)(b * LSEQ + l)) * 384 + e] : 0.f;
    }
    __syncthreads();

    for (int i = tid; i < 16 * 192; i += 256) {
        int lt = i / 192, e = i % 192;
        float v = conv_b[e];
#pragma unroll
        for (int k = 0; k < 4; k++) v += conv_w[e * 4 + k] * pre[lt + k][e];
        float sil = v / (1.f + __expf(-v));
        xsl[lt][e] = sil;
        xs_g[((size_t)(b * LSEQ + l0 + lt)) * DI + e] = sil;
    }
    __syncthreads();

    for (int i = tid; i < 16 * 38; i += 256) {
        int lt = i / 38, o = i % 38;
        float a = 0.f;
        for (int e = 0; e < DI; e += 4) {
            float4 xv = *(const float4*)&xsl[lt][e];
            float4 w  = *(const float4*)&Wx_l[o][e];
            a += xv.x * w.x + xv.y * w.y + xv.z * w.z + xv.w * w.w;
        }
        dbc[lt][o] = a;
    }
    __syncthreads();

    for (int i = tid; i < 16 * 192; i += 256) {
        int lt = i / 192, e = i % 192;
        float a = b_dt[e];
#pragma unroll
        for (int r = 0; r < RNK; r++) a += dbc[lt][r] * Wdt_t[r][e];
        float d = (a > 20.f) ? a : log1pf(__expf(a));
        delta_g[((size_t)(b * LSEQ + l0 + lt)) * DI + e] = d;
    }
    for (int i = tid; i < 16 * 32; i += 256) {
        int lt = i / 32, o = i % 32;
        float v = dbc[lt][RNK + o];
        size_t base = ((size_t)(b * LSEQ + l0 + lt)) * NST;
        if (o < NST) Bm_g[base + o] = v;
        else         Cm_g[base + (o - NST)] = v;
    }
}

// ---------------- k3a: per-chunk aggregates ----------------
__global__ __launch_bounds__(256) void k3a_chunk(const float* __restrict__ delta_g,
                                                 const float* __restrict__ xs_g,
                                                 const float* __restrict__ Bm_g,
                                                 const float* __restrict__ A_log,
                                                 float* __restrict__ Ap_g,
                                                 float* __restrict__ Bs_g) {
    int gid = blockIdx.x * 16 + (threadIdx.x >> 4);
    int n = threadIdx.x & 15;
    int e = gid % DI;
    int t = gid / DI;
    int c = t & (NC - 1);
    int b = t >> 5;

    float A_th = -__expf(A_log[e * NST + n]);
    size_t lbase = (size_t)b * LSEQ + (size_t)c * CS;
    const float* dp = delta_g + lbase * DI + e;
    const float* xp = xs_g + lbase * DI + e;
    const float* bp = Bm_g + lbase * NST + n;

    float ap = 1.f, bs = 0.f;
    for (int l = 0; l < CS; l++) {
        float d = dp[(size_t)l * DI];
        float xv = xp[(size_t)l * DI];
        float bm = bp[(size_t)l * NST];
        float a = __expf(d * A_th);
        ap *= a;
        bs = bs * a + d * xv * bm;
    }
    size_t idx = (((size_t)(b * DI + e)) * NC + c) * NST + n;
    Ap_g[idx] = ap;
    Bs_g[idx] = bs;
}

// ---------------- k3b: scan over chunk aggregates ----------------
__global__ __launch_bounds__(256) void k3b_combine(const float* __restrict__ Ap_g,
                                                   const float* __restrict__ Bs_g,
                                                   float* __restrict__ h0_g) {
    int i = blockIdx.x * 256 + threadIdx.x;
    int n = i & 15;
    int be = i >> 4;
    size_t base = ((size_t)be * NC) * NST + n;
    float h = 0.f;
    for (int c = 0; c < NC; c++) {
        h0_g[base + (size_t)c * NST] = h;
        h = Ap_g[base + (size_t)c * NST] * h + Bs_g[base + (size_t)c * NST];
    }
}

// ---------------- k3c: within-chunk recompute + y + fused gating ----------------
// writes g = (y + D*xs) * silu(z)  TRANSPOSED: g[(b*DI+e)*LSEQ + l]
__global__ __launch_bounds__(256) void k3c_scan(const float* __restrict__ delta_g,
                                                const float* __restrict__ xs_g,
                                                const float* __restrict__ Bm_g,
                                                const float* __restrict__ Cm_g,
                                                const float* __restrict__ A_log,
                                                const float* __restrict__ h0_g,
                                                const float* __restrict__ xz,
                                                const float* __restrict__ D_param,
                                                float* __restrict__ g_t) {
    int gid = blockIdx.x * 16 + (threadIdx.x >> 4);
    int n = threadIdx.x & 15;
    int e = gid % DI;
    int t = gid / DI;
    int c = t & (NC - 1);
    int b = t >> 5;

    float A_th = -__expf(A_log[e * NST + n]);
    float Dp = D_param[e];
    float h = h0_g[(((size_t)(b * DI + e)) * NC + c) * NST + n];
    size_t lbase = (size_t)b * LSEQ + (size_t)c * CS;
    const float* dp = delta_g + lbase * DI + e;
    const float* xp = xs_g + lbase * DI + e;
    const float* bp = Bm_g + lbase * NST + n;
    const float* cp = Cm_g + lbase * NST + n;
    const float* zp = xz + lbase * 384 + 192 + e;
    float* gp = g_t + ((size_t)(b * DI + e)) * LSEQ + (size_t)c * CS;

    for (int l = 0; l < CS; l++) {
        float d = dp[(size_t)l * DI];
        float xv = xp[(size_t)l * DI];
        float bm = bp[(size_t)l * NST];
        float cm = cp[(size_t)l * NST];
        float a = __expf(d * A_th);
        h = a * h + d * xv * bm;
        float y = h * cm;
        y += __shfl_xor(y, 1, 64);
        y += __shfl_xor(y, 2, 64);
        y += __shfl_xor(y, 4, 64);
        y += __shfl_xor(y, 8, 64);
        if (n == 0) {
            float z = zp[(size_t)l * 384];
            float yt = (y + Dp * xv) * (z / (1.f + __expf(-z)));
            gp[l] = yt;
        }
    }
}

// ---------------- k4: out-proj + residual ----------------
// grid 512 = 256 token-groups x 2 j-halves; block 256 (4 waves), 12 j per wave.
__global__ __launch_bounds__(256) void k4_outproj(const float* __restrict__ x,
                                                  const float* __restrict__ g_t,
                                                  const float* __restrict__ W_out,
                                                  float* __restrict__ out) {
    int blk = blockIdx.x;
    int tg = blk >> 1;
    int jh = blk & 1;
    int lane = threadIdx.x & 63;
    int wv = __builtin_amdgcn_readfirstlane(threadIdx.x >> 6);
    int b = tg >> 6;
    int l = ((tg & 63) << 6) | lane;

    const float* gp = g_t + ((size_t)b * DI) * LSEQ + l;
    int j0 = jh * 48 + wv * 12;
    float acc[12];
#pragma unroll
    for (int jj = 0; jj < 12; jj++) acc[jj] = 0.f;

    float gr[96];
#pragma unroll
    for (int c = 0; c < 96; c++) gr[c] = gp[(size_t)c * LSEQ];   // coalesced
    for (int jj = 0; jj < 12; jj++) {
        const float* w = W_out + (size_t)(j0 + jj) * 192;        // uniform
        float a = acc[jj];
#pragma unroll
        for (int c = 0; c < 96; c++) a += gr[c] * w[c];
        acc[jj] = a;
    }
#pragma unroll
    for (int c = 0; c < 96; c++) gr[c] = gp[(size_t)(96 + c) * LSEQ];
    for (int jj = 0; jj < 12; jj++) {
        const float* w = W_out + (size_t)(j0 + jj) * 192 + 96;
        float a = acc[jj];
#pragma unroll
        for (int c = 0; c < 96; c++) a += gr[c] * w[c];
        acc[jj] = a;
    }

#pragma unroll
    for (int jj = 0; jj < 12; jj++) {
        int ch = j0 + jj;
        size_t oi = ((size_t)(b * DM + ch)) * LSEQ + l;
        out[oi] = acc[jj] + x[oi];                               // coalesced
    }
}

extern "C" void kernel_launch(void* const* d_in, const int* in_sizes, int n_in,
                              void* d_out, int out_size, void* d_ws, size_t ws_size,
                              hipStream_t stream) {
    const float* x      = (const float*)d_in[0];
    const float* W_in   = (const float*)d_in[1];
    const float* conv_w = (const float*)d_in[2];
    const float* conv_b = (const float*)d_in[3];
    const float* W_x    = (const float*)d_in[4];
    const float* W_dt   = (const float*)d_in[5];
    const float* b_dt   = (const float*)d_in[6];
    const float* A_log  = (const float*)d_in[7];
    const float* D_par  = (const float*)d_in[8];
    const float* W_out  = (const float*)d_in[9];
    const float* norm_w = (const float*)d_in[10];
    float* out = (float*)d_out;
    float* ws  = (float*)d_ws;

    // ws layout (floats)
    float* xz    = ws;                      // 16384*384   = 6291456
    float* xs    = ws + 6291456;            // 3145728
    float* delta = ws + 9437184;            // 3145728
    float* Bm    = ws + 12582912;           // 262144
    float* Cm    = ws + 12845056;           // 262144
    float* Ap    = ws + 13107200;           // 393216
    float* Bs    = ws + 13500416;           // 393216
    float* h0    = ws + 13893632;           // 393216
    float* g_t   = ws + 14286848;           // 3145728 (transposed gated output)

    k1_inproj<<<512, 256, 0, stream>>>(x, W_in, norm_w, xz);
    k2_conv_proj<<<1024, 256, 0, stream>>>(xz, conv_w, conv_b, W_x, W_dt, b_dt,
                                           xs, delta, Bm, Cm);
    k3a_chunk<<<1536, 256, 0, stream>>>(delta, xs, Bm, A_log, Ap, Bs);
    k3b_combine<<<48, 256, 0, stream>>>(Ap, Bs, h0);
    k3c_scan<<<1536, 256, 0, stream>>>(delta, xs, Bm, Cm, A_log, h0, xz, D_par, g_t);
    k4_outproj<<<512, 256, 0, stream>>>(x, g_t, W_out, out);
}

// Round 3
// 251.867 us; speedup vs baseline: 2.2191x; 1.1939x over previous
//
#include <hip/hip_runtime.h>
#include <hip/hip_bf16.h>

// Vim (Vision Mamba) block forward, fp32.
// B=4, C=D_MODEL=96, L=4096, D_INNER=192, DT_RANK=6, N=16, K=4.
//   k1: RMSNorm + in-proj (96->384)        [token-per-lane, uniform W loads]
//   k2: conv(K=4)+SiLU + x-proj + dt-proj  [W_x/W_dt staged in LDS]
//   k3a/k3b/k3c: chunked scan, ALL 16 states in registers per thread
//                (lanes = e, coalesced d/x, uniform B/C); k3c fuses gating and
//                transposes g via LDS -> coalesced channel-major g_t
//   k4: out-proj (192->96) + residual      [token-per-lane, uniform W loads]

#define DM   96
#define DI   192
#define LSEQ 4096
#define NB   4
#define RNK  6
#define NST  16
#define LOG2E 1.44269504088896f

// ---------------- k1: RMSNorm + in-proj ----------------
__global__ __launch_bounds__(256) void k1_inproj(const float* __restrict__ x,
                                                 const float* __restrict__ W_in,
                                                 const float* __restrict__ norm_w,
                                                 float* __restrict__ xz) {
    int blk = blockIdx.x;
    int tg = blk >> 1;
    int jh = blk & 1;
    int lane = threadIdx.x & 63;
    int wv = __builtin_amdgcn_readfirstlane(threadIdx.x >> 6);
    int b = tg >> 6;
    int l = ((tg & 63) << 6) | lane;

    const float* xb = x + (size_t)b * DM * LSEQ + l;
    float xn[96];
    float ss = 0.f;
#pragma unroll
    for (int c = 0; c < 96; c++) {
        float v = xb[(size_t)c * LSEQ];
        xn[c] = v;
        ss += v * v;
    }
    float rstd = rsqrtf(ss * (1.0f / 96.0f) + 1e-5f);
#pragma unroll
    for (int c = 0; c < 96; c++) xn[c] *= rstd * norm_w[c];

    int j0 = jh * 192 + wv * 48;
    float* o = xz + ((size_t)(b * LSEQ + l)) * 384;
    for (int jc = 0; jc < 12; jc++) {
        int j = j0 + jc * 4;
        const float* w0 = W_in + (size_t)j * 96;
        float a0 = 0.f, a1 = 0.f, a2 = 0.f, a3 = 0.f;
#pragma unroll
        for (int c = 0; c < 96; c++) {
            float xv = xn[c];
            a0 += xv * w0[c];
            a1 += xv * w0[96 + c];
            a2 += xv * w0[192 + c];
            a3 += xv * w0[288 + c];
        }
        *(float4*)&o[j] = make_float4(a0, a1, a2, a3);
    }
}

// ---------------- k2: conv + SiLU + x-proj + dt-proj ----------------
__global__ __launch_bounds__(256) void k2_conv_proj(const float* __restrict__ xz,
                                                    const float* __restrict__ conv_w,
                                                    const float* __restrict__ conv_b,
                                                    const float* __restrict__ W_x,
                                                    const float* __restrict__ W_dt,
                                                    const float* __restrict__ b_dt,
                                                    float* __restrict__ xs_g,
                                                    float* __restrict__ delta_g,
                                                    float* __restrict__ Bm_g,
                                                    float* __restrict__ Cm_g) {
    int blk = blockIdx.x;
    int b = blk >> 8;
    int l0 = (blk & 255) * 16;
    int tid = threadIdx.x;
    __shared__ float pre[19][192];
    __shared__ float xsl[16][196];
    __shared__ float Wx_l[38][196];
    __shared__ float Wdt_t[RNK][192];
    __shared__ float dbc[16][38];

    for (int i = tid; i < 38 * 192; i += 256) Wx_l[i / 192][i % 192] = W_x[i];
    for (int i = tid; i < 192 * RNK; i += 256) Wdt_t[i % RNK][i / RNK] = W_dt[i];
    for (int i = tid; i < 19 * 192; i += 256) {
        int r = i / 192, e = i % 192;
        int l = l0 - 3 + r;
        pre[r][e] = (l >= 0) ? xz[((size_t)(b * LSEQ + l)) * 384 + e] : 0.f;
    }
    __syncthreads();

    for (int i = tid; i < 16 * 192; i += 256) {
        int lt = i / 192, e = i % 192;
        float v = conv_b[e];
#pragma unroll
        for (int k = 0; k < 4; k++) v += conv_w[e * 4 + k] * pre[lt + k][e];
        float sil = v / (1.f + __expf(-v));
        xsl[lt][e] = sil;
        xs_g[((size_t)(b * LSEQ + l0 + lt)) * DI + e] = sil;
    }
    __syncthreads();

    for (int i = tid; i < 16 * 38; i += 256) {
        int lt = i / 38, o = i % 38;
        float a = 0.f;
        for (int e = 0; e < DI; e += 4) {
            float4 xv = *(const float4*)&xsl[lt][e];
            float4 w  = *(const float4*)&Wx_l[o][e];
            a += xv.x * w.x + xv.y * w.y + xv.z * w.z + xv.w * w.w;
        }
        dbc[lt][o] = a;
    }
    __syncthreads();

    for (int i = tid; i < 16 * 192; i += 256) {
        int lt = i / 192, e = i % 192;
        float a = b_dt[e];
#pragma unroll
        for (int r = 0; r < RNK; r++) a += dbc[lt][r] * Wdt_t[r][e];
        float d = (a > 20.f) ? a : log1pf(__expf(a));
        delta_g[((size_t)(b * LSEQ + l0 + lt)) * DI + e] = d;
    }
    for (int i = tid; i < 16 * 32; i += 256) {
        int lt = i / 32, o = i % 32;
        float v = dbc[lt][RNK + o];
        size_t base = ((size_t)(b * LSEQ + l0 + lt)) * NST;
        if (o < NST) Bm_g[base + o] = v;
        else         Cm_g[base + (o - NST)] = v;
    }
}

// ---------------- k3a: per-chunk aggregates, 16 states per thread ----------------
// grid NB*NC blocks x 192 threads; thread e = tid; block = (b, c).
// Ap/Bs layout: [(b*NC+c)*3072 + q*768 + e*4 + r], n = 4q+r.
template<int NC, int CS>
__global__ __launch_bounds__(192) void k3a_chunk(const float* __restrict__ delta_g,
                                                 const float* __restrict__ xs_g,
                                                 const float* __restrict__ Bm_g,
                                                 const float* __restrict__ A_log,
                                                 float* __restrict__ Ap_g,
                                                 float* __restrict__ Bs_g) {
    int b = blockIdx.x / NC;
    int c = blockIdx.x % NC;
    int e = threadIdx.x;

    float A2[NST];
#pragma unroll
    for (int q = 0; q < 4; q++) {
        float4 al = *(const float4*)&A_log[e * NST + q * 4];
        A2[q * 4 + 0] = -__expf(al.x) * LOG2E;
        A2[q * 4 + 1] = -__expf(al.y) * LOG2E;
        A2[q * 4 + 2] = -__expf(al.z) * LOG2E;
        A2[q * 4 + 3] = -__expf(al.w) * LOG2E;
    }

    size_t lbase = (size_t)b * LSEQ + (size_t)c * CS;
    const float* dp = delta_g + lbase * DI + e;
    const float* xp = xs_g + lbase * DI + e;
    const float* bp = Bm_g + lbase * NST;

    float ap[NST], bs[NST];
#pragma unroll
    for (int n = 0; n < NST; n++) { ap[n] = 1.f; bs[n] = 0.f; }

#pragma unroll 2
    for (int l = 0; l < CS; l++) {
        float d  = dp[(size_t)l * DI];
        float xv = xp[(size_t)l * DI];
        float dx = d * xv;
        const float4* bm4 = (const float4*)&bp[(size_t)l * NST];
#pragma unroll
        for (int q = 0; q < 4; q++) {
            float4 bm = bm4[q];
#pragma unroll
            for (int r = 0; r < 4; r++) {
                int n = q * 4 + r;
                float bmv = (r == 0) ? bm.x : (r == 1) ? bm.y : (r == 2) ? bm.z : bm.w;
                float a = exp2f(d * A2[n]);
                ap[n] *= a;
                bs[n] = fmaf(bs[n], a, dx * bmv);
            }
        }
    }
    size_t sb = (size_t)(b * NC + c) * 3072;
#pragma unroll
    for (int q = 0; q < 4; q++) {
        *(float4*)&Ap_g[sb + q * 768 + e * 4] =
            make_float4(ap[q*4+0], ap[q*4+1], ap[q*4+2], ap[q*4+3]);
        *(float4*)&Bs_g[sb + q * 768 + e * 4] =
            make_float4(bs[q*4+0], bs[q*4+1], bs[q*4+2], bs[q*4+3]);
    }
}

// ---------------- k3b: scan over chunk aggregates ----------------
// NOTE: h0_g may alias Ap_g (loads precede the store each iteration; no __restrict).
template<int NC>
__global__ __launch_bounds__(256) void k3b_combine(const float* Ap_g,
                                                   const float* Bs_g,
                                                   float* h0_g) {
    int i = blockIdx.x * 256 + threadIdx.x;      // [0, 12288)
    int b = i / 3072;
    int rem = i % 3072;
    size_t base = (size_t)b * NC * 3072 + rem;
    float h = 0.f;
    for (int c = 0; c < NC; c++) {
        float a = Ap_g[base];
        float bsv = Bs_g[base];
        h0_g[base] = h;
        h = fmaf(a, h, bsv);
        base += 3072;
    }
}

// ---------------- k3c: within-chunk recompute + y + gating + LDS transpose ----------------
template<int NC, int CS>
__global__ __launch_bounds__(192) void k3c_scan(const float* __restrict__ delta_g,
                                                const float* __restrict__ xs_g,
                                                const float* __restrict__ Bm_g,
                                                const float* __restrict__ Cm_g,
                                                const float* __restrict__ A_log,
                                                const float* __restrict__ h0_g,
                                                const float* __restrict__ xz,
                                                const float* __restrict__ D_param,
                                                float* __restrict__ g_t) {
    __shared__ float g_lds[DI * (CS + 1)];
    int b = blockIdx.x / NC;
    int c = blockIdx.x % NC;
    int e = threadIdx.x;

    float A2[NST];
#pragma unroll
    for (int q = 0; q < 4; q++) {
        float4 al = *(const float4*)&A_log[e * NST + q * 4];
        A2[q * 4 + 0] = -__expf(al.x) * LOG2E;
        A2[q * 4 + 1] = -__expf(al.y) * LOG2E;
        A2[q * 4 + 2] = -__expf(al.z) * LOG2E;
        A2[q * 4 + 3] = -__expf(al.w) * LOG2E;
    }
    float Dp = D_param[e];

    float h[NST];
    size_t hb = (size_t)(b * NC + c) * 3072;
#pragma unroll
    for (int q = 0; q < 4; q++) {
        float4 hv = *(const float4*)&h0_g[hb + q * 768 + e * 4];
        h[q*4+0] = hv.x; h[q*4+1] = hv.y; h[q*4+2] = hv.z; h[q*4+3] = hv.w;
    }

    size_t lbase = (size_t)b * LSEQ + (size_t)c * CS;
    const float* dp = delta_g + lbase * DI + e;
    const float* xp = xs_g + lbase * DI + e;
    const float* bp = Bm_g + lbase * NST;
    const float* cp = Cm_g + lbase * NST;
    const float* zp = xz + lbase * 384 + 192 + e;

#pragma unroll 2
    for (int l = 0; l < CS; l++) {
        float d  = dp[(size_t)l * DI];
        float xv = xp[(size_t)l * DI];
        float z  = zp[(size_t)l * 384];
        float dx = d * xv;
        const float4* bm4 = (const float4*)&bp[(size_t)l * NST];
        const float4* cm4 = (const float4*)&cp[(size_t)l * NST];
        float y0 = 0.f, y1 = 0.f, y2 = 0.f, y3 = 0.f;
#pragma unroll
        for (int q = 0; q < 4; q++) {
            float4 bm = bm4[q];
            float4 cm = cm4[q];
            {
                int n = q * 4 + 0;
                float a = exp2f(d * A2[n]);
                h[n] = fmaf(h[n], a, dx * bm.x);
                y0 = fmaf(h[n], cm.x, y0);
            }
            {
                int n = q * 4 + 1;
                float a = exp2f(d * A2[n]);
                h[n] = fmaf(h[n], a, dx * bm.y);
                y1 = fmaf(h[n], cm.y, y1);
            }
            {
                int n = q * 4 + 2;
                float a = exp2f(d * A2[n]);
                h[n] = fmaf(h[n], a, dx * bm.z);
                y2 = fmaf(h[n], cm.z, y2);
            }
            {
                int n = q * 4 + 3;
                float a = exp2f(d * A2[n]);
                h[n] = fmaf(h[n], a, dx * bm.w);
                y3 = fmaf(h[n], cm.w, y3);
            }
        }
        float y = (y0 + y1) + (y2 + y3);
        float g = (y + Dp * xv) * (z / (1.f + __expf(-z)));
        g_lds[e * (CS + 1) + l] = g;
    }
    __syncthreads();

    // coalesced write-out: g_t[(b*DI+e)*LSEQ + c*CS + l]
    float* gt = g_t + ((size_t)b * DI) * LSEQ + (size_t)c * CS;
    for (int idx = threadIdx.x; idx < DI * CS; idx += 192) {
        int e_w = idx / CS;
        int l_w = idx & (CS - 1);
        gt[(size_t)e_w * LSEQ + l_w] = g_lds[e_w * (CS + 1) + l_w];
    }
}

// ---------------- k4: out-proj + residual ----------------
__global__ __launch_bounds__(256) void k4_outproj(const float* __restrict__ x,
                                                  const float* __restrict__ g_t,
                                                  const float* __restrict__ W_out,
                                                  float* __restrict__ out) {
    int blk = blockIdx.x;
    int tg = blk >> 1;
    int jh = blk & 1;
    int lane = threadIdx.x & 63;
    int wv = __builtin_amdgcn_readfirstlane(threadIdx.x >> 6);
    int b = tg >> 6;
    int l = ((tg & 63) << 6) | lane;

    const float* gp = g_t + ((size_t)b * DI) * LSEQ + l;
    int j0 = jh * 48 + wv * 12;
    float acc[12];
#pragma unroll
    for (int jj = 0; jj < 12; jj++) acc[jj] = 0.f;

    float gr[96];
#pragma unroll
    for (int c = 0; c < 96; c++) gr[c] = gp[(size_t)c * LSEQ];
    for (int jj = 0; jj < 12; jj++) {
        const float* w = W_out + (size_t)(j0 + jj) * 192;
        float a = acc[jj];
#pragma unroll
        for (int c = 0; c < 96; c++) a += gr[c] * w[c];
        acc[jj] = a;
    }
#pragma unroll
    for (int c = 0; c < 96; c++) gr[c] = gp[(size_t)(96 + c) * LSEQ];
    for (int jj = 0; jj < 12; jj++) {
        const float* w = W_out + (size_t)(j0 + jj) * 192 + 96;
        float a = acc[jj];
#pragma unroll
        for (int c = 0; c < 96; c++) a += gr[c] * w[c];
        acc[jj] = a;
    }

#pragma unroll
    for (int jj = 0; jj < 12; jj++) {
        int ch = j0 + jj;
        size_t oi = ((size_t)(b * DM + ch)) * LSEQ + l;
        out[oi] = acc[jj] + x[oi];
    }
}

extern "C" void kernel_launch(void* const* d_in, const int* in_sizes, int n_in,
                              void* d_out, int out_size, void* d_ws, size_t ws_size,
                              hipStream_t stream) {
    const float* x      = (const float*)d_in[0];
    const float* W_in   = (const float*)d_in[1];
    const float* conv_w = (const float*)d_in[2];
    const float* conv_b = (const float*)d_in[3];
    const float* W_x    = (const float*)d_in[4];
    const float* W_dt   = (const float*)d_in[5];
    const float* b_dt   = (const float*)d_in[6];
    const float* A_log  = (const float*)d_in[7];
    const float* D_par  = (const float*)d_in[8];
    const float* W_out  = (const float*)d_in[9];
    const float* norm_w = (const float*)d_in[10];
    float* out = (float*)d_out;
    float* ws  = (float*)d_ws;

    // fixed-offset buffers (floats)
    float* xz    = ws;                      // 6291456
    float* xs    = ws + 6291456;            // 3145728
    float* delta = ws + 9437184;            // 3145728
    float* Bm    = ws + 12582912;           // 262144
    float* Cm    = ws + 12845056;           // 262144
    float* tail  = ws + 13107200;           // Ap | Bs | g_t

    k1_inproj<<<512, 256, 0, stream>>>(x, W_in, norm_w, xz);
    k2_conv_proj<<<1024, 256, 0, stream>>>(xz, conv_w, conv_b, W_x, W_dt, b_dt,
                                           xs, delta, Bm, Cm);

    // NC=128 path needs (13107200 + 2*1572864 + 3145728)*4 = 77,594,624 bytes
    if (ws_size >= (size_t)77594624) {
        constexpr int NC = 128, CS = 32;
        size_t ap_sz = (size_t)NB * NC * DI * NST;     // 1572864
        float* Ap  = tail;
        float* Bs  = tail + ap_sz;
        float* g_t = tail + 2 * ap_sz;
        float* h0  = Ap;                                // alias (safe in k3b)
        k3a_chunk<NC, CS><<<NB * NC, 192, 0, stream>>>(delta, xs, Bm, A_log, Ap, Bs);
        k3b_combine<NC><<<48, 256, 0, stream>>>(Ap, Bs, h0);
        k3c_scan<NC, CS><<<NB * NC, 192, 0, stream>>>(delta, xs, Bm, Cm, A_log, h0,
                                                      xz, D_par, g_t);
        k4_outproj<<<512, 256, 0, stream>>>(x, g_t, W_out, out);
    } else {
        constexpr int NC = 32, CS = 128;                // fits proven 68.2 MB
        size_t ap_sz = (size_t)NB * NC * DI * NST;      // 393216
        float* Ap  = tail;
        float* Bs  = tail + ap_sz;
        float* g_t = tail + 2 * ap_sz;
        float* h0  = Ap;
        k3a_chunk<NC, CS><<<NB * NC, 192, 0, stream>>>(delta, xs, Bm, A_log, Ap, Bs);
        k3b_combine<NC><<<48, 256, 0, stream>>>(Ap, Bs, h0);
        k3c_scan<NC, CS><<<NB * NC, 192, 0, stream>>>(delta, xs, Bm, Cm, A_log, h0,
                                                      xz, D_par, g_t);
        k4_outproj<<<512, 256, 0, stream>>>(x, g_t, W_out, out);
    }
}